// Round 1
// baseline (3418.093 us; speedup 1.0000x reference)
//
#include <hip/hip_runtime.h>

// Problem constants
#define B_ 32
#define S_ 2048
#define DA 32
#define DH 128
#define DS 64
#define DS2 4096

__device__ __forceinline__ void block_sync_lds() {
  // barrier without vmcnt(0) drain: keeps global prefetch loads in flight
  asm volatile("s_waitcnt lgkmcnt(0)\n\ts_barrier" ::: "memory");
}

// ---------------------------------------------------------------------------
// Kernel 1: h1 = relu(relu(actions@w0 + b0)@w1 + b1)  for a chunk of tokens.
// Token index within chunk: tl = s_local*32 + b  (s-major so phase-3 reads are
// contiguous per step). 64 tokens per block, 256 threads, 4x8 microtile.
// ---------------------------------------------------------------------------
__global__ __launch_bounds__(256) void k_mlp01(
    const float* __restrict__ actions, const float* __restrict__ w0,
    const float* __restrict__ b0, const float* __restrict__ w1,
    const float* __restrict__ b1, float* __restrict__ h1,
    int s_base, int SC)
{
  __shared__ float a_t[DA][64];    // [k][tok]   8 KB
  __shared__ float w0_l[DA][DH];   // [k][f]    16 KB
  __shared__ float h0t[DH][64];    // [f][tok]  32 KB
  const int tid = threadIdx.x;
  const int m0 = blockIdx.x * 64;  // chunk-local token offset

  // stage actions transposed into LDS
#pragma unroll
  for (int q = 0; q < 2; ++q) {
    int g = tid + 256 * q;              // float4 id, 512 total
    int tok = g >> 3, kq = g & 7;
    int tl = m0 + tok;
    int b = tl & 31, s = s_base + (tl >> 5);
    float4 v = *(const float4*)(actions + ((size_t)b * S_ + s) * DA + 4 * kq);
    a_t[4 * kq + 0][tok] = v.x; a_t[4 * kq + 1][tok] = v.y;
    a_t[4 * kq + 2][tok] = v.z; a_t[4 * kq + 3][tok] = v.w;
  }
  // stage w0 (straight copy, layout [k][f])
#pragma unroll
  for (int q = 0; q < 4; ++q) {
    int g = tid + 256 * q;              // 1024 float4
    ((float4*)&w0_l[0][0])[g] = ((const float4*)w0)[g];
  }
  __syncthreads();

  const int tm = tid & 15;   // token quad: tokens 4*tm..4*tm+3
  const int tn = tid >> 4;   // feature octet: feats 8*tn..8*tn+7 (tn 0..15)

  // ---- layer 0 ----
  float acc[4][8];
#pragma unroll
  for (int mi = 0; mi < 4; ++mi)
#pragma unroll
    for (int ni = 0; ni < 8; ++ni) acc[mi][ni] = 0.f;

#pragma unroll 4
  for (int k = 0; k < DA; ++k) {
    float4 a4 = *(const float4*)&a_t[k][4 * tm];
    float4 wa = *(const float4*)&w0_l[k][8 * tn];
    float4 wb = *(const float4*)&w0_l[k][8 * tn + 4];
    float av[4] = {a4.x, a4.y, a4.z, a4.w};
    float wv[8] = {wa.x, wa.y, wa.z, wa.w, wb.x, wb.y, wb.z, wb.w};
#pragma unroll
    for (int mi = 0; mi < 4; ++mi)
#pragma unroll
      for (int ni = 0; ni < 8; ++ni) acc[mi][ni] += av[mi] * wv[ni];
  }
  {
    float4 ba = *(const float4*)(b0 + 8 * tn);
    float4 bb = *(const float4*)(b0 + 8 * tn + 4);
    float bv[8] = {ba.x, ba.y, ba.z, ba.w, bb.x, bb.y, bb.z, bb.w};
#pragma unroll
    for (int mi = 0; mi < 4; ++mi)
#pragma unroll
      for (int ni = 0; ni < 8; ++ni)
        h0t[8 * tn + ni][4 * tm + mi] = fmaxf(acc[mi][ni] + bv[ni], 0.f);
  }
  __syncthreads();

  // ---- layer 1 ----  (w1 read straight from global; 64 KB, L1/L2-hot)
  float acc1[4][8];
#pragma unroll
  for (int mi = 0; mi < 4; ++mi)
#pragma unroll
    for (int ni = 0; ni < 8; ++ni) acc1[mi][ni] = 0.f;

#pragma unroll 4
  for (int k = 0; k < DH; ++k) {
    float4 h4 = *(const float4*)&h0t[k][4 * tm];
    float4 wa = *(const float4*)(w1 + (size_t)k * DH + 8 * tn);
    float4 wb = *(const float4*)(w1 + (size_t)k * DH + 8 * tn + 4);
    float av[4] = {h4.x, h4.y, h4.z, h4.w};
    float wv[8] = {wa.x, wa.y, wa.z, wa.w, wb.x, wb.y, wb.z, wb.w};
#pragma unroll
    for (int mi = 0; mi < 4; ++mi)
#pragma unroll
      for (int ni = 0; ni < 8; ++ni) acc1[mi][ni] += av[mi] * wv[ni];
  }
  {
    float4 ba = *(const float4*)(b1 + 8 * tn);
    float4 bb = *(const float4*)(b1 + 8 * tn + 4);
    float bv[8] = {ba.x, ba.y, ba.z, ba.w, bb.x, bb.y, bb.z, bb.w};
#pragma unroll
    for (int mi = 0; mi < 4; ++mi) {
      float4 o0, o1;
      o0.x = fmaxf(acc1[mi][0] + bv[0], 0.f);
      o0.y = fmaxf(acc1[mi][1] + bv[1], 0.f);
      o0.z = fmaxf(acc1[mi][2] + bv[2], 0.f);
      o0.w = fmaxf(acc1[mi][3] + bv[3], 0.f);
      o1.x = fmaxf(acc1[mi][4] + bv[4], 0.f);
      o1.y = fmaxf(acc1[mi][5] + bv[5], 0.f);
      o1.z = fmaxf(acc1[mi][6] + bv[6], 0.f);
      o1.w = fmaxf(acc1[mi][7] + bv[7], 0.f);
      float* dst = h1 + (size_t)(m0 + 4 * tm + mi) * DH + 8 * tn;
      *(float4*)dst = o0;
      *(float4*)(dst + 4) = o1;
    }
  }
}

// ---------------------------------------------------------------------------
// Kernel 2: trans[token][n] = h1[token][:] @ w2[:][n] + b2[n]
// fp32 GEMM, 128 threads/block, tile M=64 x N=64, full K=128 in LDS.
// Thread microtile 4(m) x 8(n): 48 B LDS read per 64 FLOP -> FMA-bound.
// grid.x = n-tiles (fast dim) so concurrent blocks share A-tiles via L2/L3.
// ---------------------------------------------------------------------------
__global__ __launch_bounds__(128) void k_trans(
    const float* __restrict__ h1, const float* __restrict__ w2,
    const float* __restrict__ b2, float* __restrict__ trans)
{
  __shared__ float At[DH][64];  // [k][m] 32 KB
  __shared__ float Bt[DH][64];  // [k][n] 32 KB
  const int tid = threadIdx.x;
  const int n0 = blockIdx.x * 64;
  const int m0 = blockIdx.y * 64;

  // stage A (transpose h1 rows -> [k][m])
#pragma unroll
  for (int q = 0; q < 16; ++q) {
    int g = q * 128 + tid;         // 2048 float4
    int tok = g >> 5, kq = g & 31;
    float4 v = *(const float4*)(h1 + (size_t)(m0 + tok) * DH + 4 * kq);
    At[4 * kq + 0][tok] = v.x; At[4 * kq + 1][tok] = v.y;
    At[4 * kq + 2][tok] = v.z; At[4 * kq + 3][tok] = v.w;
  }
  // stage B (straight, [k][n])
#pragma unroll
  for (int q = 0; q < 16; ++q) {
    int g = q * 128 + tid;
    int k = g >> 4, nq = g & 15;
    *(float4*)&Bt[k][4 * nq] =
        *(const float4*)(w2 + (size_t)k * DS2 + n0 + 4 * nq);
  }
  __syncthreads();

  const int tm = tid & 15;   // m quad
  const int tn = tid >> 4;   // n octet (0..7)
  float acc[4][8];
#pragma unroll
  for (int mi = 0; mi < 4; ++mi)
#pragma unroll
    for (int ni = 0; ni < 8; ++ni) acc[mi][ni] = 0.f;

#pragma unroll 4
  for (int k = 0; k < DH; ++k) {
    float4 a4 = *(const float4*)&At[k][4 * tm];
    float4 wa = *(const float4*)&Bt[k][8 * tn];
    float4 wb = *(const float4*)&Bt[k][8 * tn + 4];
    float av[4] = {a4.x, a4.y, a4.z, a4.w};
    float wv[8] = {wa.x, wa.y, wa.z, wa.w, wb.x, wb.y, wb.z, wb.w};
#pragma unroll
    for (int mi = 0; mi < 4; ++mi)
#pragma unroll
      for (int ni = 0; ni < 8; ++ni) acc[mi][ni] += av[mi] * wv[ni];
  }

  float4 ba = *(const float4*)(b2 + n0 + 8 * tn);
  float4 bb = *(const float4*)(b2 + n0 + 8 * tn + 4);
  float bv[8] = {ba.x, ba.y, ba.z, ba.w, bb.x, bb.y, bb.z, bb.w};
#pragma unroll
  for (int mi = 0; mi < 4; ++mi) {
    float4 o0, o1;
    o0.x = acc[mi][0] + bv[0]; o0.y = acc[mi][1] + bv[1];
    o0.z = acc[mi][2] + bv[2]; o0.w = acc[mi][3] + bv[3];
    o1.x = acc[mi][4] + bv[4]; o1.y = acc[mi][5] + bv[5];
    o1.z = acc[mi][6] + bv[6]; o1.w = acc[mi][7] + bv[7];
    float* dst = trans + (size_t)(m0 + 4 * tm + mi) * DS2 + n0 + 8 * tn;
    *(float4*)dst = o0;
    *(float4*)(dst + 4) = o1;
  }
}

// ---------------------------------------------------------------------------
// Kernel 3: sequential RNN.  One block per batch element, 4 waves.
// Wave w owns i in [16w, 16w+16); lane = output feature j.
// T held in registers (prefetch distance 4), h broadcast via intra-wave shfl,
// cross-wave partial reduce via double-buffered LDS + ONE raw barrier/step.
// ---------------------------------------------------------------------------
__global__ __launch_bounds__(256) void k_rnn(
    const float* __restrict__ trans, const float* __restrict__ init_hidden,
    float* __restrict__ hstate, float* __restrict__ out,
    int s_base, int SC, int chunk)
{
  __shared__ float part[2][4][64];
  const int tid = threadIdx.x;
  const int b = blockIdx.x;
  const int w = tid >> 6;
  const int lane = tid & 63;

  float h;
  if (chunk == 0) {
    float ih = init_hidden[lane];
    float ss = ih * ih;
#pragma unroll
    for (int o = 1; o < 64; o <<= 1) ss += __shfl_xor(ss, o, 64);
    h = ih / fmaxf(sqrtf(ss), 1e-12f);
  } else {
    h = hstate[b * 64 + lane];
  }

  // wave-w slice of T for (chunk-local) step s lives at:
  //   trans + (s*32 + b)*4096 + (16w + t)*64 + lane ,  t = 0..15
  const float* tb = trans + (size_t)b * DS2 + (size_t)(w * 16) * DS + lane;
  float tre[4][16];
#pragma unroll
  for (int d = 0; d < 4; ++d) {
    const float* p = tb + (size_t)d * (32 * DS2);
#pragma unroll
    for (int t = 0; t < 16; ++t) tre[d][t] = p[t * DS];
  }

  int cur = 0;
  float* outp = out + ((size_t)b * S_ + s_base) * DS + lane;

  for (int s0 = 0; s0 < SC; s0 += 4) {
#pragma unroll
    for (int d = 0; d < 4; ++d) {
      const int s = s0 + d;
      // partial matvec over this wave's i-range (2 accumulator chains)
      float p0 = 0.f, p1 = 0.f;
#pragma unroll
      for (int t = 0; t < 16; t += 2) {
        p0 += __shfl(h, 16 * w + t, 64) * tre[d][t];
        p1 += __shfl(h, 16 * w + t + 1, 64) * tre[d][t + 1];
      }
      part[cur][w][lane] = p0 + p1;

      // prefetch T[s+4] into the register set just consumed (stays in
      // flight across the raw barrier below — no vmcnt drain)
      int sp = s + 4; if (sp > SC - 1) sp = SC - 1;
      {
        const float* p = tb + (size_t)sp * (32 * DS2);
#pragma unroll
        for (int t = 0; t < 16; ++t) tre[d][t] = p[t * DS];
      }

      block_sync_lds();

      float r = part[cur][0][lane] + part[cur][1][lane] +
                part[cur][2][lane] + part[cur][3][lane];
      r = fmaxf(r, 0.f);
      float ss = r * r;
#pragma unroll
      for (int o = 1; o < 64; o <<= 1) ss += __shfl_xor(ss, o, 64);
      h = r / fmaxf(sqrtf(ss), 1e-12f);
      if (w == 0) outp[(size_t)s * DS] = h;
      cur ^= 1;
    }
  }
  if (w == 0) hstate[b * 64 + lane] = h;
}

// ---------------------------------------------------------------------------
extern "C" void kernel_launch(void* const* d_in, const int* in_sizes, int n_in,
                              void* d_out, int out_size, void* d_ws, size_t ws_size,
                              hipStream_t stream) {
  const float* actions     = (const float*)d_in[0];
  const float* w0          = (const float*)d_in[1];
  const float* b0          = (const float*)d_in[2];
  const float* w1          = (const float*)d_in[3];
  const float* b1          = (const float*)d_in[4];
  const float* w2          = (const float*)d_in[5];
  const float* b2          = (const float*)d_in[6];
  const float* init_hidden = (const float*)d_in[7];
  float* out = (float*)d_out;

  // pick the largest sequence chunk whose transitions fit in ws
  int SC = 2048;
  while (SC > 4) {
    size_t need = (size_t)SC * 32 * DS2 * 4   // transitions chunk
                + (size_t)SC * 32 * DH * 4    // h1 chunk
                + 64 * 4;                     // hidden-state carry
    if (need <= ws_size) break;
    SC >>= 1;
  }
  float* trans  = (float*)d_ws;
  float* h1     = trans + (size_t)SC * 32 * DS2;
  float* hstate = h1 + (size_t)SC * 32 * DH;

  const int nch = S_ / SC;
  for (int c = 0; c < nch; ++c) {
    int s_base = c * SC;
    hipLaunchKernelGGL(k_mlp01, dim3(SC / 2), dim3(256), 0, stream,
                       actions, w0, b0, w1, b1, h1, s_base, SC);
    hipLaunchKernelGGL(k_trans, dim3(64, SC / 2), dim3(128), 0, stream,
                       h1, w2, b2, trans);
    hipLaunchKernelGGL(k_rnn, dim3(32), dim3(256), 0, stream,
                       trans, init_hidden, hstate, out, s_base, SC, c);
  }
}

// Round 3
// 2586.837 us; speedup vs baseline: 1.3213x; 1.3213x over previous
//
#include <hip/hip_runtime.h>

// Problem constants
#define B_ 32
#define S_ 2048
#define DA 32
#define DH 128
#define DS 64
#define DS2 4096

__device__ __forceinline__ void block_sync_lds() {
  // barrier without vmcnt(0) drain: keeps global prefetch loads in flight
  asm volatile("s_waitcnt lgkmcnt(0)\n\ts_barrier" ::: "memory");
}

template <int CTRL>
__device__ __forceinline__ float dpp_add(float x) {
  int t = __builtin_amdgcn_update_dpp(0, __float_as_int(x), CTRL, 0xF, 0xF, true);
  return x + __int_as_float(t);
}
__device__ __forceinline__ float rl(float x, int lane) {
  return __int_as_float(__builtin_amdgcn_readlane(__float_as_int(x), lane));
}
// sum across 64 lanes, result uniform in all lanes (4 DPP + 4 readlane)
__device__ __forceinline__ float wave_sum64(float x) {
  x = dpp_add<0xB1>(x);   // quad_perm xor1
  x = dpp_add<0x4E>(x);   // quad_perm xor2
  x = dpp_add<0x141>(x);  // row_half_mirror (combine 4-groups)
  x = dpp_add<0x140>(x);  // row_mirror (combine 8-groups) -> row-of-16 uniform
  return (rl(x, 0) + rl(x, 16)) + (rl(x, 32) + rl(x, 48));
}

// ---------------------------------------------------------------------------
// Kernel 1: h1t[f][tok] = relu(relu(actions@w0 + b0)@w1 + b1)  (TRANSPOSED out)
// 64 tokens per block, 256 threads, 4x8 microtile. M = SC*32 tokens per chunk.
// ---------------------------------------------------------------------------
__global__ __launch_bounds__(256) void k_mlp01(
    const float* __restrict__ actions, const float* __restrict__ w0,
    const float* __restrict__ b0, const float* __restrict__ w1,
    const float* __restrict__ b1, float* __restrict__ h1t,
    int s_base, int M)
{
  __shared__ float a_t[DA][64];    // [k][tok]   8 KB
  __shared__ float w0_l[DA][DH];   // [k][f]    16 KB
  __shared__ float h0t[DH][64];    // [f][tok]  32 KB
  const int tid = threadIdx.x;
  const int m0 = blockIdx.x * 64;  // chunk-local token offset

#pragma unroll
  for (int q = 0; q < 2; ++q) {
    int g = tid + 256 * q;              // float4 id, 512 total
    int tok = g >> 3, kq = g & 7;
    int tl = m0 + tok;
    int b = tl & 31, s = s_base + (tl >> 5);
    float4 v = *(const float4*)(actions + ((size_t)b * S_ + s) * DA + 4 * kq);
    a_t[4 * kq + 0][tok] = v.x; a_t[4 * kq + 1][tok] = v.y;
    a_t[4 * kq + 2][tok] = v.z; a_t[4 * kq + 3][tok] = v.w;
  }
#pragma unroll
  for (int q = 0; q < 4; ++q) {
    int g = tid + 256 * q;              // 1024 float4
    ((float4*)&w0_l[0][0])[g] = ((const float4*)w0)[g];
  }
  __syncthreads();

  const int tm = tid & 15;   // token quad
  const int tn = tid >> 4;   // feature octet (0..15)

  float acc[4][8];
#pragma unroll
  for (int mi = 0; mi < 4; ++mi)
#pragma unroll
    for (int ni = 0; ni < 8; ++ni) acc[mi][ni] = 0.f;

#pragma unroll 4
  for (int k = 0; k < DA; ++k) {
    float4 a4 = *(const float4*)&a_t[k][4 * tm];
    float4 wa = *(const float4*)&w0_l[k][8 * tn];
    float4 wb = *(const float4*)&w0_l[k][8 * tn + 4];
    float av[4] = {a4.x, a4.y, a4.z, a4.w};
    float wv[8] = {wa.x, wa.y, wa.z, wa.w, wb.x, wb.y, wb.z, wb.w};
#pragma unroll
    for (int mi = 0; mi < 4; ++mi)
#pragma unroll
      for (int ni = 0; ni < 8; ++ni) acc[mi][ni] += av[mi] * wv[ni];
  }
  {
    float4 ba = *(const float4*)(b0 + 8 * tn);
    float4 bb = *(const float4*)(b0 + 8 * tn + 4);
    float bv[8] = {ba.x, ba.y, ba.z, ba.w, bb.x, bb.y, bb.z, bb.w};
#pragma unroll
    for (int mi = 0; mi < 4; ++mi)
#pragma unroll
      for (int ni = 0; ni < 8; ++ni)
        h0t[8 * tn + ni][4 * tm + mi] = fmaxf(acc[mi][ni] + bv[ni], 0.f);
  }
  __syncthreads();

  float acc1[4][8];
#pragma unroll
  for (int mi = 0; mi < 4; ++mi)
#pragma unroll
    for (int ni = 0; ni < 8; ++ni) acc1[mi][ni] = 0.f;

#pragma unroll 4
  for (int k = 0; k < DH; ++k) {
    float4 h4 = *(const float4*)&h0t[k][4 * tm];
    float4 wa = *(const float4*)(w1 + (size_t)k * DH + 8 * tn);
    float4 wb = *(const float4*)(w1 + (size_t)k * DH + 8 * tn + 4);
    float av[4] = {h4.x, h4.y, h4.z, h4.w};
    float wv[8] = {wa.x, wa.y, wa.z, wa.w, wb.x, wb.y, wb.z, wb.w};
#pragma unroll
    for (int mi = 0; mi < 4; ++mi)
#pragma unroll
      for (int ni = 0; ni < 8; ++ni) acc1[mi][ni] += av[mi] * wv[ni];
  }
  {
    float4 ba = *(const float4*)(b1 + 8 * tn);
    float4 bb = *(const float4*)(b1 + 8 * tn + 4);
    float bv[8] = {ba.x, ba.y, ba.z, ba.w, bb.x, bb.y, bb.z, bb.w};
#pragma unroll
    for (int ni = 0; ni < 8; ++ni) {
      float4 o;
      o.x = fmaxf(acc1[0][ni] + bv[ni], 0.f);
      o.y = fmaxf(acc1[1][ni] + bv[ni], 0.f);
      o.z = fmaxf(acc1[2][ni] + bv[ni], 0.f);
      o.w = fmaxf(acc1[3][ni] + bv[ni], 0.f);
      // transposed store: h1t[feat][token], coalesced across tm
      *(float4*)(h1t + (size_t)(8 * tn + ni) * M + m0 + 4 * tm) = o;
    }
  }
}

// ---------------------------------------------------------------------------
// Kernel 2: trans = h1t^T @ w2 + b2.  fp32, 256 threads, tile 128x128,
// microtile 4m x 16n (64 FMA per 80 LDS-bytes, conflict-free reads),
// K-tile 32 double-buffered in LDS (64 KB -> 2 blocks/CU), register-staged,
// ONE __syncthreads per K-tile; next tile's global loads issued before compute.
// ---------------------------------------------------------------------------
#define TMT 128
#define TNT 128
#define TKT 32
__global__ __launch_bounds__(256, 2) void k_trans(
    const float* __restrict__ h1t, const float* __restrict__ w2,
    const float* __restrict__ b2, float* __restrict__ trans, int M)
{
  __shared__ float As[2][TKT][TMT];  // 16 KB x2
  __shared__ float Bs[2][TKT][TNT];  // 16 KB x2
  const int tid = threadIdx.x;
  const int n0 = blockIdx.x * TNT;
  const int m0 = blockIdx.y * TMT;

  float4 ra[4], rb[4];
  // stage tile t: 4096 floats each for A,B; thread g-th float4, g = tid+256q
  auto gload = [&](int t) {
#pragma unroll
    for (int q = 0; q < 4; ++q) {
      int g = tid + 256 * q;
      int k = g >> 5, mq = g & 31;     // k 0..31, quad 0..31
      ra[q] = *(const float4*)(h1t + (size_t)(t * TKT + k) * M + m0 + 4 * mq);
      rb[q] = *(const float4*)(w2 + (size_t)(t * TKT + k) * DS2 + n0 + 4 * mq);
    }
  };
  auto lwrite = [&](int buf) {
#pragma unroll
    for (int q = 0; q < 4; ++q) {
      int g = tid + 256 * q;
      int k = g >> 5, mq = g & 31;
      *(float4*)&As[buf][k][4 * mq] = ra[q];
      *(float4*)&Bs[buf][k][4 * mq] = rb[q];
    }
  };

  gload(0);
  lwrite(0);

  const int tmq = tid & 31;   // m-quad: m = 4*tmq
  const int tn  = tid >> 5;   // n-16-group: n = 16*tn
  float acc[4][16];
#pragma unroll
  for (int mi = 0; mi < 4; ++mi)
#pragma unroll
    for (int ni = 0; ni < 16; ++ni) acc[mi][ni] = 0.f;

#pragma unroll
  for (int t = 0; t < 4; ++t) {
    if (t < 3) gload(t + 1);
    __syncthreads();
    const int buf = t & 1;
#pragma unroll
    for (int k = 0; k < TKT; ++k) {
      float4 a4 = *(const float4*)&As[buf][k][4 * tmq];
      float av[4] = {a4.x, a4.y, a4.z, a4.w};
      float bv[16];
#pragma unroll
      for (int j = 0; j < 4; ++j) {
        float4 b4 = *(const float4*)&Bs[buf][k][16 * tn + 4 * j];
        bv[4 * j + 0] = b4.x; bv[4 * j + 1] = b4.y;
        bv[4 * j + 2] = b4.z; bv[4 * j + 3] = b4.w;
      }
#pragma unroll
      for (int mi = 0; mi < 4; ++mi)
#pragma unroll
        for (int ni = 0; ni < 16; ++ni) acc[mi][ni] += av[mi] * bv[ni];
    }
    if (t < 3) lwrite((t + 1) & 1);
  }

  float bv[16];
#pragma unroll
  for (int j = 0; j < 4; ++j) {
    float4 b4 = *(const float4*)(b2 + n0 + 16 * tn + 4 * j);
    bv[4 * j + 0] = b4.x; bv[4 * j + 1] = b4.y;
    bv[4 * j + 2] = b4.z; bv[4 * j + 3] = b4.w;
  }
#pragma unroll
  for (int mi = 0; mi < 4; ++mi) {
    float* dst = trans + (size_t)(m0 + 4 * tmq + mi) * DS2 + n0 + 16 * tn;
#pragma unroll
    for (int j = 0; j < 4; ++j) {
      float4 o;
      o.x = acc[mi][4 * j + 0] + bv[4 * j + 0];
      o.y = acc[mi][4 * j + 1] + bv[4 * j + 1];
      o.z = acc[mi][4 * j + 2] + bv[4 * j + 2];
      o.w = acc[mi][4 * j + 3] + bv[4 * j + 3];
      *(float4*)(dst + 4 * j) = o;
    }
  }
}

// ---------------------------------------------------------------------------
// Kernel 3: sequential RNN.  One block per batch element, 4 waves.
// Wave w owns i in [16w, 16w+16); lane = output feature j.
// T in registers (prefetch depth 4); h broadcast via v_readlane (scalar pipe);
// norm via DPP reduce; cross-wave partial reduce: LDS + ONE raw barrier/step.
// ---------------------------------------------------------------------------
__global__ __launch_bounds__(256) void k_rnn(
    const float* __restrict__ trans, const float* __restrict__ init_hidden,
    float* __restrict__ hstate, float* __restrict__ out,
    int s_base, int SC, int chunk)
{
  __shared__ float part[2][4][64];
  const int tid = threadIdx.x;
  const int b = blockIdx.x;
  const int w = tid >> 6;
  const int lane = tid & 63;

  float h;
  if (chunk == 0) {
    float ih = init_hidden[lane];
    float ss = wave_sum64(ih * ih);
    h = ih / fmaxf(sqrtf(ss), 1e-12f);
  } else {
    h = hstate[b * 64 + lane];
  }

  // wave-w slice of T for chunk-local step s:
  //   trans + (s*32 + b)*4096 + (16w + t)*64 + lane ,  t = 0..15
  const float* tb = trans + (size_t)b * DS2 + (size_t)(w * 16) * DS + lane;
  float tre[4][16];
#pragma unroll
  for (int d = 0; d < 4; ++d) {
    const float* p = tb + (size_t)d * (32 * DS2);
#pragma unroll
    for (int t = 0; t < 16; ++t) tre[d][t] = p[t * DS];
  }

  int cur = 0;
  float* outp = out + ((size_t)b * S_ + s_base) * DS + lane;

  for (int s0 = 0; s0 < SC; s0 += 4) {
#pragma unroll
    for (int d = 0; d < 4; ++d) {
      const int s = s0 + d;
      // partial matvec over this wave's i-range; h[i] via readlane (uniform idx)
      float p0 = 0.f, p1 = 0.f;
#pragma unroll
      for (int t = 0; t < 16; t += 2) {
        p0 += rl(h, 16 * w + t) * tre[d][t];
        p1 += rl(h, 16 * w + t + 1) * tre[d][t + 1];
      }
      part[cur][w][lane] = p0 + p1;

      // prefetch T[s+4] into the register set just consumed
      int sp = s + 4; if (sp > SC - 1) sp = SC - 1;
      {
        const float* p = tb + (size_t)sp * (32 * DS2);
#pragma unroll
        for (int t = 0; t < 16; ++t) tre[d][t] = p[t * DS];
      }

      block_sync_lds();

      float r = part[cur][0][lane] + part[cur][1][lane] +
                part[cur][2][lane] + part[cur][3][lane];
      r = fmaxf(r, 0.f);
      float ss = wave_sum64(r * r);
      h = r / fmaxf(sqrtf(ss), 1e-12f);
      if (w == 0) outp[(size_t)s * DS] = h;
      cur ^= 1;
    }
  }
  if (w == 0) hstate[b * 64 + lane] = h;
}

// ---------------------------------------------------------------------------
extern "C" void kernel_launch(void* const* d_in, const int* in_sizes, int n_in,
                              void* d_out, int out_size, void* d_ws, size_t ws_size,
                              hipStream_t stream) {
  const float* actions     = (const float*)d_in[0];
  const float* w0          = (const float*)d_in[1];
  const float* b0          = (const float*)d_in[2];
  const float* w1          = (const float*)d_in[3];
  const float* b1          = (const float*)d_in[4];
  const float* w2          = (const float*)d_in[5];
  const float* b2          = (const float*)d_in[6];
  const float* init_hidden = (const float*)d_in[7];
  float* out = (float*)d_out;

  // pick the largest sequence chunk whose transitions fit in ws
  int SC = 2048;
  while (SC > 4) {
    size_t need = (size_t)SC * 32 * DS2 * 4   // transitions chunk
                + (size_t)SC * 32 * DH * 4    // h1t chunk
                + 64 * 4;                     // hidden-state carry
    if (need <= ws_size) break;
    SC >>= 1;
  }
  float* trans  = (float*)d_ws;
  float* h1t    = trans + (size_t)SC * 32 * DS2;
  float* hstate = h1t + (size_t)SC * 32 * DH;

  const int M = SC * 32;
  const int nch = S_ / SC;
  for (int c = 0; c < nch; ++c) {
    int s_base = c * SC;
    hipLaunchKernelGGL(k_mlp01, dim3(M / 64), dim3(256), 0, stream,
                       actions, w0, b0, w1, b1, h1t, s_base, M);
    hipLaunchKernelGGL(k_trans, dim3(DS2 / TNT, M / TMT), dim3(256), 0, stream,
                       h1t, w2, b2, trans, M);
    hipLaunchKernelGGL(k_rnn, dim3(32), dim3(256), 0, stream,
                       trans, init_hidden, hstate, out, s_base, SC, c);
  }
}